// Round 1
// baseline (1178.666 us; speedup 1.0000x reference)
//
#include <hip/hip_runtime.h>
#include <hip/hip_bf16.h>

// Problem: LSTM  B=256, S=512, I=512, H=128, OUT=2
// Pipeline:
//   K1 pack:  Wi (512x512 f32) -> bf16 B-fragment layout; Wh (128x512 f32) -> same
//   K2 gemm:  xg[s*256+b][g] = sum_i x[b][s][i]*Wi[i][g]   (bf16 MFMA, out bf16)
//   K3 lstm:  512 sequential steps, 16 WGs x 16 batch rows, Wh-frags in VGPRs,
//             c fp32 in regs, h via LDS bf16; fused logits epilogue.

typedef __attribute__((ext_vector_type(8))) short short8;     // 8 bf16 (4 VGPR)
typedef __attribute__((ext_vector_type(4))) float floatx4;    // MFMA C/D
typedef __attribute__((ext_vector_type(4))) unsigned short ushortx4;

#define LOG2E 1.44269504088896340736f

__device__ __forceinline__ unsigned short f2bf(float f) {
  unsigned int u = __builtin_bit_cast(unsigned int, f);
  u = (u + 0x7fffu + ((u >> 16) & 1u)) >> 16;   // RNE
  return (unsigned short)u;
}
__device__ __forceinline__ float bf2f(unsigned short u) {
  unsigned int v = ((unsigned int)u) << 16;
  return __builtin_bit_cast(float, v);
}
__device__ __forceinline__ float sigf(float x) {
  // 1/(1+e^-x); saturates correctly at +-inf
  return __builtin_amdgcn_rcpf(1.0f + __builtin_amdgcn_exp2f(-LOG2E * x));
}
__device__ __forceinline__ float tanhf_(float x) {
  // 1 - 2/(1+e^{2x})
  return 1.0f - 2.0f * __builtin_amdgcn_rcpf(1.0f + __builtin_amdgcn_exp2f(2.0f * LOG2E * x));
}

// ---------------- K1: pack Wi and Wh into B-fragment order (bf16) -------------
// B-frag layout for mfma_f32_16x16x32_bf16: lane holds B[k=quad*8+j][n=lane&15]
// packed[( (kk*32 + ntile)*64 + lane )*8 + j] = W[kk*32 + (lane>>4)*8 + j][ntile*16 + (lane&15)]
__global__ void pack_kernel(const float* __restrict__ Wi, const float* __restrict__ Wh,
                            unsigned short* __restrict__ Wi_p, unsigned short* __restrict__ Wh_p) {
  int idx = blockIdx.x * 256 + threadIdx.x;
  if (idx < 262144) {                      // Wi: kk 0..15, nt 0..31
    int j = idx & 7, lane = (idx >> 3) & 63, nt = (idx >> 9) & 31, kk = idx >> 14;
    int k = kk * 32 + ((lane >> 4) * 8) + j;
    int n = nt * 16 + (lane & 15);
    Wi_p[idx] = f2bf(Wi[k * 512 + n]);
  } else {                                 // Wh: kk 0..3, nt 0..31
    int i2 = idx - 262144;
    int j = i2 & 7, lane = (i2 >> 3) & 63, nt = (i2 >> 9) & 31, kk = i2 >> 14;
    int k = kk * 32 + ((lane >> 4) * 8) + j;
    int n = nt * 16 + (lane & 15);
    Wh_p[i2] = f2bf(Wh[k * 512 + n]);
  }
}

// ---------------- K2: xg = x @ Wi (bf16 MFMA) ---------------------------------
// Grid: x = bn (4 tiles of N=512), y = bm (1024 tiles of M=131072). BM=BN=128, BK=64.
// Row (s*256+b) of A is x[b][s][:]; a 128-row tile has fixed s, b in [b0,b0+128).
__global__ __launch_bounds__(256) void xgemm_kernel(
    const float* __restrict__ x, const unsigned short* __restrict__ Wi_p,
    unsigned short* __restrict__ xg) {
  __shared__ __align__(16) unsigned short As[128 * 72];  // 72-elem row stride (144B, 16B-aligned)

  int bn = blockIdx.x;           // 0..3
  int bm = blockIdx.y;           // 0..1023
  int tid = threadIdx.x;
  int lane = tid & 63;
  int w = tid >> 6;
  int wm = w >> 1, wn = w & 1;
  int quad = lane >> 4;
  int lm = lane & 15;

  int s = bm >> 1;
  int b0 = (bm & 1) * 128;

  floatx4 acc[4][4];
  #pragma unroll
  for (int a = 0; a < 4; ++a)
    #pragma unroll
    for (int b2 = 0; b2 < 4; ++b2) { acc[a][b2].x = 0.f; acc[a][b2].y = 0.f; acc[a][b2].z = 0.f; acc[a][b2].w = 0.f; }

  for (int kt = 0; kt < 8; ++kt) {
    int k0 = kt * 64;
    __syncthreads();   // previous iter's frag reads complete
    // stage A tile 128x64 f32 -> bf16 LDS. lane covers cols lm*4..lm*4+4, rows w*32+i*4+quad
    #pragma unroll
    for (int i = 0; i < 8; ++i) {
      int r = w * 32 + i * 4 + quad;
      const float* src = x + ((size_t)(b0 + r) * 512 + s) * 512 + k0 + lm * 4;
      floatx4 v = *(const floatx4*)src;
      ushortx4 u;
      u.x = f2bf(v.x); u.y = f2bf(v.y); u.z = f2bf(v.z); u.w = f2bf(v.w);
      *(ushortx4*)(&As[r * 72 + lm * 4]) = u;
    }
    __syncthreads();
    #pragma unroll
    for (int ks = 0; ks < 2; ++ks) {
      int kkg = kt * 2 + ks;
      short8 af[4];
      #pragma unroll
      for (int mt = 0; mt < 4; ++mt) {
        int m = wm * 64 + mt * 16 + lm;
        af[mt] = *(const short8*)(&As[m * 72 + ks * 32 + quad * 8]);
      }
      #pragma unroll
      for (int nt = 0; nt < 4; ++nt) {
        int ntg = bn * 8 + wn * 4 + nt;
        short8 bfv = *(const short8*)(Wi_p + ((size_t)(kkg * 32 + ntg) * 64 + lane) * 8);
        #pragma unroll
        for (int mt = 0; mt < 4; ++mt)
          acc[mt][nt] = __builtin_amdgcn_mfma_f32_16x16x32_bf16(af[mt], bfv, acc[mt][nt], 0, 0, 0);
      }
    }
  }
  // epilogue: C layout col=lane&15, row=quad*4+reg
  #pragma unroll
  for (int mt = 0; mt < 4; ++mt) {
    #pragma unroll
    for (int nt = 0; nt < 4; ++nt) {
      int n = bn * 128 + wn * 64 + nt * 16 + lm;
      #pragma unroll
      for (int rr = 0; rr < 4; ++rr) {
        int row = bm * 128 + wm * 64 + mt * 16 + quad * 4 + rr;
        xg[(size_t)row * 512 + n] = f2bf(acc[mt][nt][rr]);
      }
    }
  }
}

// ---------------- K3: recurrence + head ---------------------------------------
// 16 blocks x 256 threads. Block handles batch rows [b0, b0+16).
// Wave w owns j-slice [32w, 32w+32): 8 tiles t=g*2+jt (gate g, sub jt), Wh-frags in VGPRs.
__global__ __launch_bounds__(256, 1) void lstm_kernel(
    const unsigned short* __restrict__ xg, const unsigned short* __restrict__ Wh_p,
    const float* __restrict__ bias, const float* __restrict__ Wd,
    const float* __restrict__ bd, float* __restrict__ out) {
  __shared__ __align__(16) unsigned short hb[2][16 * 136];  // h bf16, row stride 136 (272B)

  int tid = threadIdx.x;
  int lane = tid & 63;
  int w = tid >> 6;
  int quad = lane >> 4;
  int lm = lane & 15;
  int b0 = blockIdx.x * 16;

  // zero h buffer 0 (h0 = 0)
  for (int i = tid; i < 16 * 136; i += 256) hb[0][i] = 0;

  // preload Wh B-fragments: bfr[kk][t], tile t -> gate g=t>>1, jt=t&1, ntile=g*8+w*2+jt
  short8 bfr[4][8];
  #pragma unroll
  for (int kk = 0; kk < 4; ++kk)
    #pragma unroll
    for (int t = 0; t < 8; ++t) {
      int ntg = (t >> 1) * 8 + w * 2 + (t & 1);
      bfr[kk][t] = *(const short8*)(Wh_p + ((size_t)(kk * 32 + ntg) * 64 + lane) * 8);
    }

  int colt[8];
  float bcol[8];
  #pragma unroll
  for (int t = 0; t < 8; ++t) {
    colt[t] = (t >> 1) * 128 + w * 32 + (t & 1) * 16 + lm;
    bcol[t] = bias[colt[t]];
  }

  float cst[2][4];   // cell state fp32, C layout [jt][reg]
  #pragma unroll
  for (int jt = 0; jt < 2; ++jt)
    #pragma unroll
    for (int r = 0; r < 4; ++r) cst[jt][r] = 0.f;

  const unsigned short* p0 = xg + (size_t)(b0 + quad * 4) * 512;

  // prefetch xg for s=0
  unsigned short xcur[8][4], xnxt[8][4];
  #pragma unroll
  for (int t = 0; t < 8; ++t)
    #pragma unroll
    for (int r = 0; r < 4; ++r) xcur[t][r] = p0[(size_t)r * 512 + colt[t]];

  __syncthreads();   // h zero visible

  for (int s = 0; s < 512; ++s) {
    int rp = s & 1;
    // A-frags from LDS h: A[m=lm][k=kk*32+quad*8 ..+8]
    short8 af[4];
    #pragma unroll
    for (int kk = 0; kk < 4; ++kk)
      af[kk] = *(const short8*)(&hb[rp][lm * 136 + kk * 32 + quad * 8]);

    // prefetch next step's xg (hidden behind MFMA + elementwise + barrier)
    if (s < 511) {
      #pragma unroll
      for (int t = 0; t < 8; ++t)
        #pragma unroll
        for (int r = 0; r < 4; ++r)
          xnxt[t][r] = p0[(size_t)(s + 1) * 131072 + r * 512 + colt[t]];
    }

    floatx4 acc[8];
    #pragma unroll
    for (int t = 0; t < 8; ++t) { acc[t].x = 0.f; acc[t].y = 0.f; acc[t].z = 0.f; acc[t].w = 0.f; }
    #pragma unroll
    for (int kk = 0; kk < 4; ++kk)
      #pragma unroll
      for (int t = 0; t < 8; ++t)
        acc[t] = __builtin_amdgcn_mfma_f32_16x16x32_bf16(af[kk], bfr[kk][t], acc[t], 0, 0, 0);

    // elementwise: t = g*2+jt -> i: jt, f: 2+jt, g: 4+jt, o: 6+jt
    #pragma unroll
    for (int jt = 0; jt < 2; ++jt)
      #pragma unroll
      for (int r = 0; r < 4; ++r) {
        float iv = acc[0 + jt][r] + bf2f(xcur[0 + jt][r]) + bcol[0 + jt];
        float fv = acc[2 + jt][r] + bf2f(xcur[2 + jt][r]) + bcol[2 + jt];
        float gv = acc[4 + jt][r] + bf2f(xcur[4 + jt][r]) + bcol[4 + jt];
        float ov = acc[6 + jt][r] + bf2f(xcur[6 + jt][r]) + bcol[6 + jt];
        float cc = sigf(fv) * cst[jt][r] + sigf(iv) * tanhf_(gv);
        cst[jt][r] = cc;
        float hv = sigf(ov) * tanhf_(cc);
        hb[rp ^ 1][(quad * 4 + r) * 136 + w * 32 + jt * 16 + lm] = f2bf(hv);
      }

    #pragma unroll
    for (int t = 0; t < 8; ++t)
      #pragma unroll
      for (int r = 0; r < 4; ++r) xcur[t][r] = xnxt[t][r];

    __syncthreads();
  }

  // head: h_last is in hb[0] (512 steps -> final write to buf 0). 32 threads do 16x2.
  if (tid < 32) {
    int bl = tid >> 1;
    int co = tid & 1;
    float accv = bd[co];
    for (int j = 0; j < 128; ++j)
      accv += bf2f(hb[0][bl * 136 + j]) * Wd[j * 2 + co];
    out[(b0 + bl) * 2 + co] = accv;
  }
}

extern "C" void kernel_launch(void* const* d_in, const int* in_sizes, int n_in,
                              void* d_out, int out_size, void* d_ws, size_t ws_size,
                              hipStream_t stream) {
  const float* x  = (const float*)d_in[0];   // (256,512,512)
  const float* Wi = (const float*)d_in[1];   // (512,512)
  const float* Wh = (const float*)d_in[2];   // (128,512)
  const float* b  = (const float*)d_in[3];   // (512,)
  const float* Wd = (const float*)d_in[4];   // (128,2)
  const float* bd = (const float*)d_in[5];   // (2,)
  float* out = (float*)d_out;                // (256,2) fp32

  unsigned short* Wi_p = (unsigned short*)d_ws;          // 262144 elems (512 KB)
  unsigned short* Wh_p = Wi_p + 262144;                  // 65536 elems (128 KB)
  unsigned short* xg   = Wh_p + 65536;                   // 512*256*512 bf16 (128 MB)

  pack_kernel<<<1280, 256, 0, stream>>>(Wi, Wh, Wi_p, Wh_p);
  xgemm_kernel<<<dim3(4, 1024), 256, 0, stream>>>(x, Wi_p, xg);
  lstm_kernel<<<16, 256, 0, stream>>>(xg, Wh_p, b, Wd, bd, out);
}

// Round 2
// 1001.765 us; speedup vs baseline: 1.1766x; 1.1766x over previous
//
#include <hip/hip_runtime.h>
#include <hip/hip_bf16.h>

// LSTM  B=256, S=512, I=512, H=128, OUT=2
// K1 pack:  Wi/Wh f32 -> bf16 B-fragment layout
// K2 gemm:  xg = x@Wi, BM=128 BN=256, output PRE-PERMUTED for lstm consumption:
//           xgp[(((s*4+gi)*16+bblk)*256+tid)*8 + jt*4 + r]  (16B chunk per tid)
// K3 lstm:  16 blocks x 16 batch rows; Wh-frags in VGPRs; xg staged to LDS via
//           global_load_lds (1-step double buffer); bias+xg folded into MFMA C.

typedef __attribute__((ext_vector_type(8))) short short8;      // 8 bf16
typedef __attribute__((ext_vector_type(8))) unsigned short ushort8;
typedef __attribute__((ext_vector_type(4))) float floatx4;
typedef __attribute__((ext_vector_type(4))) unsigned short ushortx4;

#define LOG2E 1.44269504088896340736f

__device__ __forceinline__ unsigned short f2bf(float f) {
  unsigned int u = __builtin_bit_cast(unsigned int, f);
  u = (u + 0x7fffu + ((u >> 16) & 1u)) >> 16;   // RNE
  return (unsigned short)u;
}
__device__ __forceinline__ float bf2f(unsigned short u) {
  unsigned int v = ((unsigned int)u) << 16;
  return __builtin_bit_cast(float, v);
}
__device__ __forceinline__ float sigf(float x) {
  return __builtin_amdgcn_rcpf(1.0f + __builtin_amdgcn_exp2f(-LOG2E * x));
}
__device__ __forceinline__ float tanhf_(float x) {
  return 1.0f - 2.0f * __builtin_amdgcn_rcpf(1.0f + __builtin_amdgcn_exp2f(2.0f * LOG2E * x));
}
__device__ __forceinline__ void gl_lds16(const void* g, void* l) {
  __builtin_amdgcn_global_load_lds(
      (const __attribute__((address_space(1))) unsigned int*)g,
      (__attribute__((address_space(3))) unsigned int*)l, 16, 0, 0);
}

// ---------------- K1: pack Wi / Wh into B-fragment order (bf16) ---------------
__global__ void pack_kernel(const float* __restrict__ Wi, const float* __restrict__ Wh,
                            unsigned short* __restrict__ Wi_p, unsigned short* __restrict__ Wh_p) {
  int idx = blockIdx.x * 256 + threadIdx.x;
  if (idx < 262144) {
    int j = idx & 7, lane = (idx >> 3) & 63, nt = (idx >> 9) & 31, kk = idx >> 14;
    int k = kk * 32 + ((lane >> 4) * 8) + j;
    int n = nt * 16 + (lane & 15);
    Wi_p[idx] = f2bf(Wi[k * 512 + n]);
  } else {
    int i2 = idx - 262144;
    int j = i2 & 7, lane = (i2 >> 3) & 63, nt = (i2 >> 9) & 31, kk = i2 >> 14;
    int k = kk * 32 + ((lane >> 4) * 8) + j;
    int n = nt * 16 + (lane & 15);
    Wh_p[i2] = f2bf(Wh[k * 512 + n]);
  }
}

// ---------------- K2: xg = x @ Wi ---------------------------------------------
// grid (2, 1024): bn = 256-col half, bm -> s = bm>>1, b0 = (bm&1)*128.
__global__ __launch_bounds__(256, 2) void xgemm_kernel(
    const float* __restrict__ x, const unsigned short* __restrict__ Wi_p,
    unsigned short* __restrict__ xgp) {
  __shared__ __align__(16) unsigned short As[128 * 72];

  int bn = blockIdx.x;
  int bm = blockIdx.y;
  int tid = threadIdx.x;
  int lane = tid & 63;
  int w = tid >> 6;
  int wm = w >> 1, wn = w & 1;
  int quad = lane >> 4;
  int lm = lane & 15;
  int s = bm >> 1;
  int b0 = (bm & 1) * 128;

  floatx4 acc[4][8];
  #pragma unroll
  for (int a = 0; a < 4; ++a)
    #pragma unroll
    for (int b2 = 0; b2 < 8; ++b2) { acc[a][b2].x = 0.f; acc[a][b2].y = 0.f; acc[a][b2].z = 0.f; acc[a][b2].w = 0.f; }

  for (int kt = 0; kt < 8; ++kt) {
    int k0 = kt * 64;
    __syncthreads();
    #pragma unroll
    for (int i = 0; i < 8; ++i) {
      int r = w * 32 + i * 4 + quad;
      const float* src = x + ((size_t)(b0 + r) * 512 + s) * 512 + k0 + lm * 4;
      floatx4 v = *(const floatx4*)src;
      ushortx4 u;
      u.x = f2bf(v.x); u.y = f2bf(v.y); u.z = f2bf(v.z); u.w = f2bf(v.w);
      *(ushortx4*)(&As[r * 72 + lm * 4]) = u;
    }
    __syncthreads();
    #pragma unroll
    for (int ks = 0; ks < 2; ++ks) {
      int kkg = kt * 2 + ks;
      short8 af[4];
      #pragma unroll
      for (int mt = 0; mt < 4; ++mt) {
        int m = wm * 64 + mt * 16 + lm;
        af[mt] = *(const short8*)(&As[m * 72 + ks * 32 + quad * 8]);
      }
      #pragma unroll
      for (int nt = 0; nt < 8; ++nt) {
        int ntg = bn * 16 + wn * 8 + nt;
        short8 bfv = *(const short8*)(Wi_p + ((size_t)(kkg * 32 + ntg) * 64 + lane) * 8);
        #pragma unroll
        for (int mt = 0; mt < 4; ++mt)
          acc[mt][nt] = __builtin_amdgcn_mfma_f32_16x16x32_bf16(af[mt], bfv, acc[mt][nt], 0, 0, 0);
      }
    }
  }
  // epilogue: permuted coalesced stores. col c = bn*256+wn*128+nt*16+lm,
  // gi = bn*2+wn, p = nt>>1, jt = nt&1; row -> bblk=(bm&1)*8+wm*4+mt, r=quad*4+rr.
  int gi = bn * 2 + wn;
  #pragma unroll
  for (int mt = 0; mt < 4; ++mt) {
    int bblk = (bm & 1) * 8 + wm * 4 + mt;
    #pragma unroll
    for (int p = 0; p < 4; ++p) {
      ushort8 v;
      #pragma unroll
      for (int jt = 0; jt < 2; ++jt)
        #pragma unroll
        for (int rr = 0; rr < 4; ++rr)
          v[jt * 4 + rr] = f2bf(acc[mt][p * 2 + jt][rr]);
      size_t off = ((((size_t)s * 4 + gi) * 16 + bblk) * 256 + p * 64 + quad * 16 + lm) * 8;
      *(ushort8*)(xgp + off) = v;
    }
  }
}

// ---------------- K3: recurrence + head ---------------------------------------
__global__ __launch_bounds__(256, 1) void lstm_kernel(
    const unsigned short* __restrict__ xgp, const unsigned short* __restrict__ Wh_p,
    const float* __restrict__ bias, const float* __restrict__ Wd,
    const float* __restrict__ bd, float* __restrict__ out) {
  __shared__ __align__(16) unsigned short hb[2][16 * 136];     // 8.5 KB
  __shared__ __align__(16) unsigned short xb[2][4 * 256 * 8];  // 32 KB, [buf][gi][tid][8]

  int tid = threadIdx.x;
  int lane = tid & 63;
  int w = tid >> 6;
  int quad = lane >> 4;
  int lm = lane & 15;
  int bblk = blockIdx.x;

  for (int i = tid; i < 16 * 136; i += 256) hb[0][i] = 0;

  // Wh B-fragments in VGPRs
  short8 bfr[4][8];
  #pragma unroll
  for (int kk = 0; kk < 4; ++kk)
    #pragma unroll
    for (int t = 0; t < 8; ++t) {
      int ntg = (t >> 1) * 8 + w * 2 + (t & 1);
      bfr[kk][t] = *(const short8*)(Wh_p + ((size_t)(kk * 32 + ntg) * 64 + lane) * 8);
    }

  float bcol[8];
  #pragma unroll
  for (int t = 0; t < 8; ++t)
    bcol[t] = bias[(t >> 1) * 128 + w * 32 + (t & 1) * 16 + lm];

  float cst[2][4];
  #pragma unroll
  for (int jt = 0; jt < 2; ++jt)
    #pragma unroll
    for (int r = 0; r < 4; ++r) cst[jt][r] = 0.f;

  const unsigned short* gbase = xgp + (size_t)bblk * 256 * 8;  // + (s*4+gi)*16*256*8 + tid*8

  // stage s=0 into xb[0]
  #pragma unroll
  for (int gi = 0; gi < 4; ++gi)
    gl_lds16(gbase + ((size_t)(0 * 4 + gi) * 16 * 256 + tid) * 8,
             &xb[0][(gi * 256 + tid) * 8]);

  __syncthreads();  // drains vmcnt: xb[0] valid, hb[0] zero visible

  for (int s = 0; s < 512; ++s) {
    int rp = s & 1;
    // h A-frags
    short8 af[4];
    #pragma unroll
    for (int kk = 0; kk < 4; ++kk)
      af[kk] = *(const short8*)(&hb[rp][lm * 136 + kk * 32 + quad * 8]);

    // prefetch next step's xg into the other buffer (completes at this step's barrier)
    if (s < 511) {
      #pragma unroll
      for (int gi = 0; gi < 4; ++gi)
        gl_lds16(gbase + ((size_t)((s + 1) * 4 + gi) * 16 * 256 + tid) * 8,
                 &xb[rp ^ 1][(gi * 256 + tid) * 8]);
    }

    // acc init = xg + bias (folded into MFMA C operand)
    floatx4 acc[8];
    #pragma unroll
    for (int p = 0; p < 4; ++p) {
      short8 xv = *(const short8*)(&xb[rp][(p * 256 + tid) * 8]);
      #pragma unroll
      for (int jt = 0; jt < 2; ++jt)
        #pragma unroll
        for (int r = 0; r < 4; ++r)
          acc[2 * p + jt][r] = bf2f((unsigned short)xv[jt * 4 + r]) + bcol[2 * p + jt];
    }

    #pragma unroll
    for (int kk = 0; kk < 4; ++kk)
      #pragma unroll
      for (int t = 0; t < 8; ++t)
        acc[t] = __builtin_amdgcn_mfma_f32_16x16x32_bf16(af[kk], bfr[kk][t], acc[t], 0, 0, 0);

    #pragma unroll
    for (int jt = 0; jt < 2; ++jt)
      #pragma unroll
      for (int r = 0; r < 4; ++r) {
        float iv = acc[0 + jt][r];
        float fv = acc[2 + jt][r];
        float gv = acc[4 + jt][r];
        float ov = acc[6 + jt][r];
        float cc = sigf(fv) * cst[jt][r] + sigf(iv) * tanhf_(gv);
        cst[jt][r] = cc;
        float hv = sigf(ov) * tanhf_(cc);
        hb[rp ^ 1][(quad * 4 + r) * 136 + w * 32 + jt * 16 + lm] = f2bf(hv);
      }

    __syncthreads();
  }

  // head: h_last in hb[0]
  if (tid < 32) {
    int bl = tid >> 1;
    int co = tid & 1;
    float accv = bd[co];
    for (int j = 0; j < 128; ++j)
      accv += bf2f(hb[0][bl * 136 + j]) * Wd[j * 2 + co];
    out[(bblk * 16 + bl) * 2 + co] = accv;
  }
}

extern "C" void kernel_launch(void* const* d_in, const int* in_sizes, int n_in,
                              void* d_out, int out_size, void* d_ws, size_t ws_size,
                              hipStream_t stream) {
  const float* x  = (const float*)d_in[0];
  const float* Wi = (const float*)d_in[1];
  const float* Wh = (const float*)d_in[2];
  const float* b  = (const float*)d_in[3];
  const float* Wd = (const float*)d_in[4];
  const float* bd = (const float*)d_in[5];
  float* out = (float*)d_out;

  unsigned short* Wi_p = (unsigned short*)d_ws;          // 512 KB
  unsigned short* Wh_p = Wi_p + 262144;                  // 128 KB
  unsigned short* xgp  = Wh_p + 65536;                   // 128 MB permuted xg

  pack_kernel<<<1280, 256, 0, stream>>>(Wi, Wh, Wi_p, Wh_p);
  xgemm_kernel<<<dim3(2, 1024), 256, 0, stream>>>(x, Wi_p, xgp);
  lstm_kernel<<<16, 256, 0, stream>>>(xgp, Wh_p, b, Wd, bd, out);
}

// Round 3
// 872.271 us; speedup vs baseline: 1.3513x; 1.1485x over previous
//
#include <hip/hip_runtime.h>
#include <hip/hip_bf16.h>

// LSTM  B=256, S=512, I=512, H=128, OUT=2
// K1 pack:  Wi/Wh f32 -> bf16 B-fragment layout
// K2 gemm:  xg = x@Wi (bf16 MFMA, reg-double-buffered staging), epilogue writes
//           4 gate planes: xgq[g][s][bb][t] uint = bf16 pair (row r0, row r0+2),
//           t = r0*128 + j, bb = batch>>2.
// K3 lstm:  64 blocks x 4 batch rows x 512 threads (8 waves, 2/SIMD TLP).
//           MFMA phase: quad0 lanes hold gate pre-acts, write fp32 -> LDS gb
//           (stride 17, conflict-free). EW phase: 1 cell/thread, xg from
//           2-step-deep register prefetch. h round-trips via LDS bf16.

typedef __attribute__((ext_vector_type(8))) short short8;      // 8 bf16
typedef __attribute__((ext_vector_type(4))) float floatx4;
typedef __attribute__((ext_vector_type(4))) unsigned short ushortx4;

#define LOG2E 1.44269504088896340736f

__device__ __forceinline__ unsigned short f2bf(float f) {
  unsigned int u = __builtin_bit_cast(unsigned int, f);
  u = (u + 0x7fffu + ((u >> 16) & 1u)) >> 16;   // RNE
  return (unsigned short)u;
}
__device__ __forceinline__ float bf2f(unsigned short u) {
  unsigned int v = ((unsigned int)u) << 16;
  return __builtin_bit_cast(float, v);
}
__device__ __forceinline__ float sigf(float x) {
  return __builtin_amdgcn_rcpf(1.0f + __builtin_amdgcn_exp2f(-LOG2E * x));
}
__device__ __forceinline__ float tanhf_(float x) {
  return 1.0f - 2.0f * __builtin_amdgcn_rcpf(1.0f + __builtin_amdgcn_exp2f(2.0f * LOG2E * x));
}

// ---------------- K1: pack Wi / Wh into B-fragment order (bf16) ---------------
__global__ void pack_kernel(const float* __restrict__ Wi, const float* __restrict__ Wh,
                            unsigned short* __restrict__ Wi_p, unsigned short* __restrict__ Wh_p) {
  int idx = blockIdx.x * 256 + threadIdx.x;
  if (idx < 262144) {
    int j = idx & 7, lane = (idx >> 3) & 63, nt = (idx >> 9) & 31, kk = idx >> 14;
    int k = kk * 32 + ((lane >> 4) * 8) + j;
    int n = nt * 16 + (lane & 15);
    Wi_p[idx] = f2bf(Wi[k * 512 + n]);
  } else {
    int i2 = idx - 262144;
    int j = i2 & 7, lane = (i2 >> 3) & 63, nt = (i2 >> 9) & 31, kk = i2 >> 14;
    int k = kk * 32 + ((lane >> 4) * 8) + j;
    int n = nt * 16 + (lane & 15);
    Wh_p[i2] = f2bf(Wh[k * 512 + n]);
  }
}

// ---------------- K2: xg = x @ Wi ---------------------------------------------
// grid (2, 1024): bn = 256-col half (2 gates), bm -> s = bm>>1, b0 = (bm&1)*128.
__global__ __launch_bounds__(256, 2) void xgemm_kernel(
    const float* __restrict__ x, const unsigned short* __restrict__ Wi_p,
    unsigned int* __restrict__ xgq) {
  __shared__ __align__(16) unsigned short As[128 * 72];

  int bn = blockIdx.x;
  int bm = blockIdx.y;
  int tid = threadIdx.x;
  int lane = tid & 63;
  int w = tid >> 6;
  int wm = w >> 1, wn = w & 1;
  int quad = lane >> 4;
  int lm = lane & 15;
  int s = bm >> 1;
  int b0 = (bm & 1) * 128;

  floatx4 acc[4][8];
  #pragma unroll
  for (int a = 0; a < 4; ++a)
    #pragma unroll
    for (int b2 = 0; b2 < 8; ++b2) { acc[a][b2].x = 0.f; acc[a][b2].y = 0.f; acc[a][b2].z = 0.f; acc[a][b2].w = 0.f; }

  // per-thread x base: row r = w*32 + i*4 + quad, col lm*4
  const float* xb_ = x + ((size_t)(b0 + w * 32 + quad) * 512 + s) * 512 + lm * 4;

  floatx4 cur[8], nxt[8];
  #pragma unroll
  for (int i = 0; i < 8; ++i)
    cur[i] = *(const floatx4*)(xb_ + (size_t)i * 1048576);

  for (int kt = 0; kt < 8; ++kt) {
    __syncthreads();   // prior compute's LDS reads complete
    if (kt < 7) {
      #pragma unroll
      for (int i = 0; i < 8; ++i)
        nxt[i] = *(const floatx4*)(xb_ + (size_t)i * 1048576 + (kt + 1) * 64);
    }
    #pragma unroll
    for (int i = 0; i < 8; ++i) {
      int r = w * 32 + i * 4 + quad;
      ushortx4 u;
      u.x = f2bf(cur[i].x); u.y = f2bf(cur[i].y); u.z = f2bf(cur[i].z); u.w = f2bf(cur[i].w);
      *(ushortx4*)(&As[r * 72 + lm * 4]) = u;
    }
    __syncthreads();
    #pragma unroll
    for (int ks = 0; ks < 2; ++ks) {
      int kkg = kt * 2 + ks;
      short8 af[4];
      #pragma unroll
      for (int mt = 0; mt < 4; ++mt) {
        int m = wm * 64 + mt * 16 + lm;
        af[mt] = *(const short8*)(&As[m * 72 + ks * 32 + quad * 8]);
      }
      #pragma unroll
      for (int nt = 0; nt < 8; ++nt) {
        int ntg = bn * 16 + wn * 8 + nt;
        short8 bfv = *(const short8*)(Wi_p + ((size_t)(kkg * 32 + ntg) * 64 + lane) * 8);
        #pragma unroll
        for (int mt = 0; mt < 4; ++mt)
          acc[mt][nt] = __builtin_amdgcn_mfma_f32_16x16x32_bf16(af[mt], bfv, acc[mt][nt], 0, 0, 0);
      }
    }
    #pragma unroll
    for (int i = 0; i < 8; ++i) cur[i] = nxt[i];
  }

  // epilogue: gate-plane stores. gate = bn*2+wn, j = nt*16+lm,
  // batch b = b0+wm*64+mt*16+quad*4+rr -> bb = b>>2, row = rr.
  // xgq[((gate*512+s)*64+bb)*256 + (row&1)*128 + j] uint: lo=row(r&1), hi=row+2
  int gate = bn * 2 + wn;
  size_t gs = ((size_t)gate * 512 + s) * 64;
  #pragma unroll
  for (int mt = 0; mt < 4; ++mt) {
    int bbv = ((b0 + wm * 64 + mt * 16) >> 2) + quad;
    size_t base = (gs + bbv) * 256;
    #pragma unroll
    for (int nt = 0; nt < 8; ++nt) {
      int j = nt * 16 + lm;
      unsigned int u0 = (unsigned int)f2bf(acc[mt][nt][0]) | ((unsigned int)f2bf(acc[mt][nt][2]) << 16);
      unsigned int u1 = (unsigned int)f2bf(acc[mt][nt][1]) | ((unsigned int)f2bf(acc[mt][nt][3]) << 16);
      xgq[base + j] = u0;
      xgq[base + 128 + j] = u1;
    }
  }
}

// ---------------- K3: recurrence + head ---------------------------------------
// 64 blocks x 512 threads; block bb owns batch rows bb*4 .. bb*4+3.
__global__ __launch_bounds__(512, 2) void lstm_kernel(
    const unsigned int* __restrict__ xgq, const unsigned short* __restrict__ Wh_p,
    const float* __restrict__ bias, const float* __restrict__ Wd,
    const float* __restrict__ bd, float* __restrict__ out) {
  __shared__ __align__(16) unsigned short hb[2][16 * 138];  // h bf16, stride 138 (odd dwords)
  __shared__ __align__(16) float gb[128 * 17];              // gate pre-acts [j][g][row], stride 17

  const int tid = threadIdx.x;
  const int lane = tid & 63;
  const int w = tid >> 6;          // 0..7
  const int quad = lane >> 4;
  const int lm = lane & 15;
  const int bb = blockIdx.x;       // 0..63

  for (int i = tid; i < 2 * 16 * 138; i += 512) ((unsigned short*)hb)[i] = 0;

  // Wh B-fragments: tile tt = gate (4 per wave), ntg = tt*8 + w
  short8 bfr[4][4];
  #pragma unroll
  for (int kk = 0; kk < 4; ++kk)
    #pragma unroll
    for (int tt = 0; tt < 4; ++tt)
      bfr[kk][tt] = *(const short8*)(Wh_p + ((size_t)(kk * 32 + tt * 8 + w) * 64 + lane) * 8);

  // EW assignment: 1 cell/thread. wave w covers rows {w>>2, (w>>2)+2}, j-slice (w&3)*32.
  const int r0 = w >> 2;                       // 0 or 1
  const int jj = (w & 3) * 32 + (lane & 31);   // 0..127
  const int row = r0 + 2 * (lane >> 5);        // this thread's row
  const int hi = lane >> 5;                    // which half of the xg uint
  float bs[4];
  #pragma unroll
  for (int g = 0; g < 4; ++g) bs[g] = bias[g * 128 + jj];
  float cst = 0.f;

  const size_t boff = (size_t)bb * 256 + (size_t)r0 * 128 + jj;
  unsigned int xga[4], xgb[4];
  #pragma unroll
  for (int g = 0; g < 4; ++g) xga[g] = xgq[(size_t)g * 8388608 + boff];
  #pragma unroll
  for (int g = 0; g < 4; ++g) xgb[g] = xgq[(size_t)g * 8388608 + 16384 + boff];

  const unsigned int* hbu = (const unsigned int*)(&hb[0][0]);

  __syncthreads();   // hb zeros visible

  auto step = [&](int s, unsigned int (&xr)[4]) {
    const int rp = s & 1;
    // A-frags: 16 scalar dword reads (stride 69 dwords/row -> conflict-free)
    short8 af[4];
    #pragma unroll
    for (int kk = 0; kk < 4; ++kk) {
      union { short8 v; unsigned int u[4]; } t;
      #pragma unroll
      for (int i = 0; i < 4; ++i)
        t.u[i] = hbu[rp * 1104 + lm * 69 + kk * 16 + quad * 4 + i];
      af[kk] = t.v;
    }
    floatx4 acc[4];
    #pragma unroll
    for (int tt = 0; tt < 4; ++tt) { acc[tt].x = 0.f; acc[tt].y = 0.f; acc[tt].z = 0.f; acc[tt].w = 0.f; }
    #pragma unroll
    for (int kk = 0; kk < 4; ++kk)
      #pragma unroll
      for (int tt = 0; tt < 4; ++tt)
        acc[tt] = __builtin_amdgcn_mfma_f32_16x16x32_bf16(af[kk], bfr[kk][tt], acc[tt], 0, 0, 0);
    // valid C rows 0..3 live in quad0 (row = quad*4+reg); scatter fp32 to gb
    if (quad == 0) {
      int jw = w * 16 + lm;
      #pragma unroll
      for (int tt = 0; tt < 4; ++tt)
        #pragma unroll
        for (int r = 0; r < 4; ++r)
          gb[jw * 17 + tt * 4 + r] = acc[tt][r];
    }
    __syncthreads();
    // EW: 1 cell/thread
    float pre[4];
    #pragma unroll
    for (int g = 0; g < 4; ++g) {
      unsigned int u = xr[g];
      unsigned short xv = hi ? (unsigned short)(u >> 16) : (unsigned short)(u & 0xffffu);
      pre[g] = gb[jj * 17 + g * 4 + row] + bf2f(xv) + bs[g];
    }
    // reload xr <- step s+2 (2-deep register prefetch; crosses barriers)
    if (s + 2 < 512) {
      #pragma unroll
      for (int g = 0; g < 4; ++g)
        xr[g] = xgq[(size_t)g * 8388608 + (size_t)(s + 2) * 16384 + boff];
    }
    float cc = sigf(pre[1]) * cst + sigf(pre[0]) * tanhf_(pre[2]);
    cst = cc;
    float hv = sigf(pre[3]) * tanhf_(cc);
    hb[rp ^ 1][row * 138 + jj] = f2bf(hv);
    __syncthreads();
  };

  for (int s = 0; s < 512; s += 2) { step(s, xga); step(s + 1, xgb); }

  // head: h_last in hb[0] (s=511 writes buf 0)
  if (tid < 8) {
    int rw = tid >> 1, co = tid & 1;
    float a = bd[co];
    for (int j2 = 0; j2 < 128; ++j2)
      a += bf2f(hb[0][rw * 138 + j2]) * Wd[j2 * 2 + co];
    out[(bb * 4 + rw) * 2 + co] = a;
  }
}

extern "C" void kernel_launch(void* const* d_in, const int* in_sizes, int n_in,
                              void* d_out, int out_size, void* d_ws, size_t ws_size,
                              hipStream_t stream) {
  const float* x  = (const float*)d_in[0];
  const float* Wi = (const float*)d_in[1];
  const float* Wh = (const float*)d_in[2];
  const float* b  = (const float*)d_in[3];
  const float* Wd = (const float*)d_in[4];
  const float* bd = (const float*)d_in[5];
  float* out = (float*)d_out;

  unsigned short* Wi_p = (unsigned short*)d_ws;          // 512 KB
  unsigned short* Wh_p = Wi_p + 262144;                  // 128 KB
  unsigned int*   xgq  = (unsigned int*)(Wh_p + 65536);  // 128 MB gate planes

  pack_kernel<<<1280, 256, 0, stream>>>(Wi, Wh, Wi_p, Wh_p);
  xgemm_kernel<<<dim3(2, 1024), 256, 0, stream>>>(x, Wi_p, xgq);
  lstm_kernel<<<64, 512, 0, stream>>>(xgq, Wh_p, b, Wd, bd, out);
}

// Round 4
// 804.489 us; speedup vs baseline: 1.4651x; 1.0843x over previous
//
#include <hip/hip_runtime.h>
#include <hip/hip_bf16.h>

// LSTM  B=256, S=512, I=512, H=128, OUT=2
// K1 pack:  Wi/Wh f32 -> bf16 B-fragment layout
// K2 gemm:  xg = x@Wi + b, 128x512 tile, 512 thr, 1024 blocks. B staged via
//           global_load_lds; epilogue stores 4-gate dwordx4 planes:
//           xg4[(((s*64+bb)*2+rh)*128+jj)*4 + g], uint = bf16{row rh, row rh+2}.
// K3 lstm:  64 blocks x 4 batch rows x 512 threads. Wh-frags in VGPRs.
//           LDS-only barriers (s_waitcnt lgkmcnt(0); s_barrier) keep the 2-deep
//           xg register prefetch in flight across steps. Gates via stride-20
//           LDS float4; h via LDS bf16 stride-138.

typedef __attribute__((ext_vector_type(8))) short short8;      // 8 bf16
typedef __attribute__((ext_vector_type(4))) float floatx4;
typedef __attribute__((ext_vector_type(4))) unsigned short ushortx4;
typedef __attribute__((ext_vector_type(4))) unsigned int uintx4;

#define LOG2E 1.44269504088896340736f

__device__ __forceinline__ unsigned short f2bf(float f) {
  unsigned int u = __builtin_bit_cast(unsigned int, f);
  u = (u + 0x7fffu + ((u >> 16) & 1u)) >> 16;   // RNE
  return (unsigned short)u;
}
__device__ __forceinline__ float bf2f(unsigned short u) {
  unsigned int v = ((unsigned int)u) << 16;
  return __builtin_bit_cast(float, v);
}
__device__ __forceinline__ float sigf(float x) {
  return __builtin_amdgcn_rcpf(1.0f + __builtin_amdgcn_exp2f(-LOG2E * x));
}
__device__ __forceinline__ float tanhf_(float x) {
  return 1.0f - 2.0f * __builtin_amdgcn_rcpf(1.0f + __builtin_amdgcn_exp2f(2.0f * LOG2E * x));
}
// LDS-only barrier: drains lgkmcnt but NOT vmcnt, so global prefetch loads
// stay in flight across step boundaries (CK block_sync_lds pattern).
__device__ __forceinline__ void bar_lds() {
  asm volatile("s_waitcnt lgkmcnt(0)" ::: "memory");
  __builtin_amdgcn_s_barrier();
}
__device__ __forceinline__ void gl_lds16(const void* g, void* l) {
  __builtin_amdgcn_global_load_lds(
      (const __attribute__((address_space(1))) unsigned int*)g,
      (__attribute__((address_space(3))) unsigned int*)l, 16, 0, 0);
}

// ---------------- K1: pack Wi / Wh into B-fragment order (bf16) ---------------
__global__ void pack_kernel(const float* __restrict__ Wi, const float* __restrict__ Wh,
                            unsigned short* __restrict__ Wi_p, unsigned short* __restrict__ Wh_p) {
  int idx = blockIdx.x * 256 + threadIdx.x;
  if (idx < 262144) {
    int j = idx & 7, lane = (idx >> 3) & 63, nt = (idx >> 9) & 31, kk = idx >> 14;
    int k = kk * 32 + ((lane >> 4) * 8) + j;
    int n = nt * 16 + (lane & 15);
    Wi_p[idx] = f2bf(Wi[k * 512 + n]);
  } else {
    int i2 = idx - 262144;
    int j = i2 & 7, lane = (i2 >> 3) & 63, nt = (i2 >> 9) & 31, kk = i2 >> 14;
    int k = kk * 32 + ((lane >> 4) * 8) + j;
    int n = nt * 16 + (lane & 15);
    Wh_p[i2] = f2bf(Wh[k * 512 + n]);
  }
}

// ---------------- K2: xg4 = x @ Wi + b (pre-permuted, bias folded) ------------
// 1024 blocks x 512 threads. s = blk>>1, b0 = (blk&1)*128. Full N=512 per block.
__global__ __launch_bounds__(512, 2) void xgemm_kernel(
    const float* __restrict__ x, const unsigned short* __restrict__ Wi_p,
    const float* __restrict__ bias, unsigned int* __restrict__ xg4) {
  __shared__ __align__(16) unsigned short As[128 * 72];        // 18.4 KB
  __shared__ __align__(16) unsigned short Bs[2 * 32 * 64 * 8]; // 64 KB

  const int tid = threadIdx.x;
  const int lane = tid & 63;
  const int w = tid >> 6;          // 0..7
  const int wm = w >> 2, wn = w & 3;
  const int quad = lane >> 4;
  const int lm = lane & 15;
  const int bm = blockIdx.x;
  const int s = bm >> 1;
  const int b0 = (bm & 1) * 128;

  float bs_[4][2];
  #pragma unroll
  for (int g = 0; g < 4; ++g)
    #pragma unroll
    for (int jc = 0; jc < 2; ++jc)
      bs_[g][jc] = bias[g * 128 + wn * 32 + jc * 16 + lm];

  floatx4 acc[4][8];
  #pragma unroll
  for (int a = 0; a < 4; ++a)
    #pragma unroll
    for (int b2 = 0; b2 < 8; ++b2) { acc[a][b2].x = 0.f; acc[a][b2].y = 0.f; acc[a][b2].z = 0.f; acc[a][b2].w = 0.f; }

  // A rows r = w*16 + i*4 + quad (i 0..3), col lm*4; batch stride 262144 floats.
  const float* xbase = x + ((size_t)(b0 + w * 16 + quad) * 512 + s) * 512 + lm * 4;

  for (int kt = 0; kt < 8; ++kt) {
    __syncthreads();   // prior compute's LDS reads done before restage
    // stage B tile (64 KB) via async global->LDS, blob (kg,ntl) = 64 lanes x 16B
    #pragma unroll
    for (int c = 0; c < 8; ++c) {
      int kg = c & 1, ntl = (c >> 1) * 8 + w;
      const unsigned short* src = Wi_p + ((size_t)((kt * 2 + kg) * 32 + ntl) * 64 + lane) * 8;
      unsigned short* dst = &Bs[(size_t)((kg * 32 + ntl) * 64) * 8];
      gl_lds16(src, dst);
    }
    // stage A tile 128x64 f32 -> bf16
    #pragma unroll
    for (int i = 0; i < 4; ++i) {
      floatx4 v = *(const floatx4*)(xbase + (size_t)i * 1048576 + kt * 64);
      int r = w * 16 + i * 4 + quad;
      ushortx4 u;
      u.x = f2bf(v.x); u.y = f2bf(v.y); u.z = f2bf(v.z); u.w = f2bf(v.w);
      *(ushortx4*)(&As[r * 72 + lm * 4]) = u;
    }
    __syncthreads();   // drains glds (vmcnt) + A writes (lgkm)
    #pragma unroll
    for (int ks = 0; ks < 2; ++ks) {
      short8 af[4];
      #pragma unroll
      for (int mt = 0; mt < 4; ++mt) {
        int m = wm * 64 + mt * 16 + lm;
        af[mt] = *(const short8*)(&As[m * 72 + ks * 32 + quad * 8]);
      }
      #pragma unroll
      for (int nt = 0; nt < 8; ++nt) {
        int g = nt >> 1, jc = nt & 1;
        int ntl = g * 8 + wn * 2 + jc;
        short8 bfv = *(const short8*)(&Bs[(size_t)((ks * 32 + ntl) * 64 + lane) * 8]);
        #pragma unroll
        for (int mt = 0; mt < 4; ++mt)
          acc[mt][nt] = __builtin_amdgcn_mfma_f32_16x16x32_bf16(af[mt], bfv, acc[mt][nt], 0, 0, 0);
      }
    }
  }
  // epilogue: 16 coalesced dwordx4 stores, bias folded.
  #pragma unroll
  for (int mt = 0; mt < 4; ++mt) {
    int bbv = ((b0 + wm * 64 + mt * 16) >> 2) + quad;
    #pragma unroll
    for (int jc = 0; jc < 2; ++jc) {
      int jj = wn * 32 + jc * 16 + lm;
      #pragma unroll
      for (int rh = 0; rh < 2; ++rh) {
        uintx4 v;
        #pragma unroll
        for (int g = 0; g < 4; ++g) {
          float lo = acc[mt][g * 2 + jc][rh]     + bs_[g][jc];
          float hi2 = acc[mt][g * 2 + jc][rh + 2] + bs_[g][jc];
          v[g] = (unsigned int)f2bf(lo) | ((unsigned int)f2bf(hi2) << 16);
        }
        *(uintx4*)(xg4 + ((((size_t)s * 64 + bbv) * 2 + rh) * 128 + jj) * 4) = v;
      }
    }
  }
}

// ---------------- K3: recurrence + head ---------------------------------------
// 64 blocks x 512 threads; block bb owns batch rows bb*4 .. bb*4+3.
__global__ __launch_bounds__(512, 2) void lstm_kernel(
    const unsigned int* __restrict__ xg4, const unsigned short* __restrict__ Wh_p,
    const float* __restrict__ Wd, const float* __restrict__ bd,
    float* __restrict__ out) {
  __shared__ __align__(16) unsigned short hb[2 * 16 * 138];  // 8.8 KB (stride 69 dwords)
  __shared__ __align__(16) float gb[128 * 20];               // 10 KB [j][row][gate]

  const int tid = threadIdx.x;
  const int lane = tid & 63;
  const int w = tid >> 6;          // 0..7
  const int quad = lane >> 4;
  const int lm = lane & 15;
  const int bb = blockIdx.x;

  for (int i = tid; i < 2 * 16 * 138; i += 512) hb[i] = 0;

  // Wh B-fragments: tile tt = gate, ntg = tt*8 + w
  short8 bfr[4][4];
  #pragma unroll
  for (int kk = 0; kk < 4; ++kk)
    #pragma unroll
    for (int tt = 0; tt < 4; ++tt)
      bfr[kk][tt] = *(const short8*)(Wh_p + ((size_t)(kk * 32 + tt * 8 + w) * 64 + lane) * 8);

  // EW: 1 cell/thread. row = r0 + 2*hi, col jj.
  const int r0 = w >> 2;
  const int jj = (w & 3) * 32 + (lane & 31);
  const int hi = lane >> 5;
  const int row = r0 + 2 * hi;
  float cst = 0.f;

  const unsigned int* xp = xg4 + ((size_t)(bb * 2 + r0) * 128 + jj) * 4;
  uintx4 xga = *(const uintx4*)(xp);              // s=0
  uintx4 xgb = *(const uintx4*)(xp + 65536);      // s=1

  const unsigned int* hbu = (const unsigned int*)hb;

  __syncthreads();   // hb zeros + initial prefetch drained (one-time)

  auto substep = [&](const int rp, uintx4& xcur, int spre) {
    uintx4 xv = xcur;   // waits the 2-steps-ago load (plenty of slack)
    if (spre < 512)
      xcur = *(const uintx4*)(xp + (size_t)spre * 65536);   // stays in flight across bar_lds

    // phase A: h A-frags from LDS, MFMA, scatter gates to gb
    short8 af[4];
    #pragma unroll
    for (int kk = 0; kk < 4; ++kk) {
      union { short8 v; unsigned int u[4]; } t;
      #pragma unroll
      for (int i = 0; i < 4; ++i)
        t.u[i] = hbu[rp * 1104 + lm * 69 + kk * 16 + quad * 4 + i];
      af[kk] = t.v;
    }
    floatx4 acc[4];
    #pragma unroll
    for (int tt = 0; tt < 4; ++tt) { acc[tt].x = 0.f; acc[tt].y = 0.f; acc[tt].z = 0.f; acc[tt].w = 0.f; }
    #pragma unroll
    for (int kk = 0; kk < 4; ++kk)
      #pragma unroll
      for (int tt = 0; tt < 4; ++tt)
        acc[tt] = __builtin_amdgcn_mfma_f32_16x16x32_bf16(af[kk], bfr[kk][tt], acc[tt], 0, 0, 0);
    if (lane < 16) {   // quad0 holds valid rows 0..3
      #pragma unroll
      for (int r = 0; r < 4; ++r) {
        floatx4 gv;
        gv.x = acc[0][r]; gv.y = acc[1][r]; gv.z = acc[2][r]; gv.w = acc[3][r];
        *(floatx4*)(gb + (w * 16 + lm) * 20 + r * 4) = gv;
      }
    }
    bar_lds();

    // phase B: EW, 1 cell/thread
    floatx4 gv = *(const floatx4*)(gb + jj * 20 + row * 4);
    float pre[4];
    #pragma unroll
    for (int g = 0; g < 4; ++g) {
      unsigned int u = xv[g];
      unsigned short xvs = hi ? (unsigned short)(u >> 16) : (unsigned short)(u & 0xffffu);
      pre[g] = gv[g] + bf2f(xvs);
    }
    float cc = sigf(pre[1]) * cst + sigf(pre[0]) * tanhf_(pre[2]);
    cst = cc;
    float hv = sigf(pre[3]) * tanhf_(cc);
    hb[(rp ^ 1) * 2208 + row * 138 + jj] = f2bf(hv);
    bar_lds();
  };

  for (int s = 0; s < 512; s += 2) {
    substep(0, xga, s + 2);
    substep(1, xgb, s + 3);
  }

  // head: h_last in hb buf 0 (s=511 writes buf 0)
  if (tid < 8) {
    int rw = tid >> 1, co = tid & 1;
    float a = bd[co];
    for (int j2 = 0; j2 < 128; ++j2)
      a += bf2f(hb[rw * 138 + j2]) * Wd[j2 * 2 + co];
    out[(bb * 4 + rw) * 2 + co] = a;
  }
}

extern "C" void kernel_launch(void* const* d_in, const int* in_sizes, int n_in,
                              void* d_out, int out_size, void* d_ws, size_t ws_size,
                              hipStream_t stream) {
  const float* x  = (const float*)d_in[0];
  const float* Wi = (const float*)d_in[1];
  const float* Wh = (const float*)d_in[2];
  const float* b  = (const float*)d_in[3];
  const float* Wd = (const float*)d_in[4];
  const float* bd = (const float*)d_in[5];
  float* out = (float*)d_out;

  unsigned short* Wi_p = (unsigned short*)d_ws;          // 512 KB
  unsigned short* Wh_p = Wi_p + 262144;                  // 128 KB
  unsigned int*   xg4  = (unsigned int*)(Wh_p + 65536);  // 128 MB

  pack_kernel<<<1280, 256, 0, stream>>>(Wi, Wh, Wi_p, Wh_p);
  xgemm_kernel<<<1024, 512, 0, stream>>>(x, Wi_p, b, xg4);
  lstm_kernel<<<64, 512, 0, stream>>>(xg4, Wh_p, Wd, bd, out);
}

// Round 5
// 752.640 us; speedup vs baseline: 1.5660x; 1.0689x over previous
//
#include <hip/hip_runtime.h>
#include <hip/hip_bf16.h>

// LSTM  B=256, S=512, I=512, H=128, OUT=2
// K1 pack:  Wi/Wh f32 -> bf16 B-fragment layout
// K2 gemm:  xg = x@Wi + b. 128x512 tile, 512 thr, 1024 blocks. B via
//           global_load_lds, A via register prefetch + partial vmcnt barrier.
//           Epilogue: per-cell 4-gate packed bf16 (8B):
//           xg5[cell*2 +0/1], cell = ((s*64+bb)*512 + wv*64 + r*16 + lm).
// K3 lstm:  64 blocks x 4 batch rows x 512 threads. ONE barrier per step:
//           af(8x ds_read_b64) -> 16 MFMA -> intra-wave LDS transpose
//           (quad0 4x ds_write_b128, lgkm wait, all-lane ds_read_b128, NO
//           barrier) -> EW 1 cell/lane -> 1x ds_write_b16 h -> bar_lds.
//           xg register-prefetched 2 steps deep across LDS-only barriers.

typedef __attribute__((ext_vector_type(8))) short short8;      // 8 bf16
typedef __attribute__((ext_vector_type(4))) float floatx4;
typedef __attribute__((ext_vector_type(4))) unsigned short ushortx4;
typedef __attribute__((ext_vector_type(2))) unsigned int uint2v;

#define LOG2E 1.44269504088896340736f

__device__ __forceinline__ unsigned short f2bf(float f) {
  unsigned int u = __builtin_bit_cast(unsigned int, f);
  u = (u + 0x7fffu + ((u >> 16) & 1u)) >> 16;   // RNE
  return (unsigned short)u;
}
__device__ __forceinline__ float bf2f(unsigned short u) {
  unsigned int v = ((unsigned int)u) << 16;
  return __builtin_bit_cast(float, v);
}
__device__ __forceinline__ float sigf(float x) {
  return __builtin_amdgcn_rcpf(1.0f + __builtin_amdgcn_exp2f(-LOG2E * x));
}
__device__ __forceinline__ float tanhf_(float x) {
  return 1.0f - 2.0f * __builtin_amdgcn_rcpf(1.0f + __builtin_amdgcn_exp2f(2.0f * LOG2E * x));
}
// LDS-only barrier: drains lgkmcnt but NOT vmcnt (global prefetch stays in flight).
__device__ __forceinline__ void bar_lds() {
  asm volatile("s_waitcnt lgkmcnt(0)" ::: "memory");
  __builtin_amdgcn_s_barrier();
}
__device__ __forceinline__ void gl_lds16(const void* g, void* l) {
  __builtin_amdgcn_global_load_lds(
      (const __attribute__((address_space(1))) unsigned int*)g,
      (__attribute__((address_space(3))) unsigned int*)l, 16, 0, 0);
}

// ---------------- K1: pack Wi / Wh into B-fragment order (bf16) ---------------
__global__ void pack_kernel(const float* __restrict__ Wi, const float* __restrict__ Wh,
                            unsigned short* __restrict__ Wi_p, unsigned short* __restrict__ Wh_p) {
  int idx = blockIdx.x * 256 + threadIdx.x;
  if (idx < 262144) {
    int j = idx & 7, lane = (idx >> 3) & 63, nt = (idx >> 9) & 31, kk = idx >> 14;
    int k = kk * 32 + ((lane >> 4) * 8) + j;
    int n = nt * 16 + (lane & 15);
    Wi_p[idx] = f2bf(Wi[k * 512 + n]);
  } else {
    int i2 = idx - 262144;
    int j = i2 & 7, lane = (i2 >> 3) & 63, nt = (i2 >> 9) & 31, kk = i2 >> 14;
    int k = kk * 32 + ((lane >> 4) * 8) + j;
    int n = nt * 16 + (lane & 15);
    Wh_p[i2] = f2bf(Wh[k * 512 + n]);
  }
}

// ---------------- K2: xg5 = x @ Wi + b (per-cell gate-packed) -----------------
__global__ __launch_bounds__(512, 2) void xgemm_kernel(
    const float* __restrict__ x, const unsigned short* __restrict__ Wi_p,
    const float* __restrict__ bias, unsigned int* __restrict__ xg5) {
  __shared__ __align__(16) unsigned short As[128 * 72];        // 18.4 KB
  __shared__ __align__(16) unsigned short Bs[2 * 32 * 64 * 8]; // 64 KB

  const int tid = threadIdx.x;
  const int lane = tid & 63;
  const int w = tid >> 6;          // 0..7
  const int wm = w >> 2, wn = w & 3;
  const int quad = lane >> 4;
  const int lm = lane & 15;
  const int bm = blockIdx.x;
  const int s = bm >> 1;
  const int b0 = (bm & 1) * 128;

  float bs_[4][2];
  #pragma unroll
  for (int g = 0; g < 4; ++g)
    #pragma unroll
    for (int jc = 0; jc < 2; ++jc)
      bs_[g][jc] = bias[g * 128 + wn * 32 + jc * 16 + lm];

  floatx4 acc[4][8];
  #pragma unroll
  for (int a = 0; a < 4; ++a)
    #pragma unroll
    for (int b2 = 0; b2 < 8; ++b2) { acc[a][b2].x = 0.f; acc[a][b2].y = 0.f; acc[a][b2].z = 0.f; acc[a][b2].w = 0.f; }

  // A rows r = w*16 + i*4 + quad (i 0..3), col lm*4; batch stride 262144 floats.
  const float* xbase = x + ((size_t)(b0 + w * 16 + quad) * 512 + s) * 512 + lm * 4;

  floatx4 cur[4], nxt[4];
  #pragma unroll
  for (int i = 0; i < 4; ++i)
    cur[i] = *(const floatx4*)(xbase + (size_t)i * 1048576);

  for (int kt = 0; kt < 8; ++kt) {
    bar_lds();   // prior compute's LDS reads done; do NOT drain vmcnt (A prefetch)
    // stage A tile from registers (compiler waits cur's vmcnt here)
    #pragma unroll
    for (int i = 0; i < 4; ++i) {
      int r = w * 16 + i * 4 + quad;
      ushortx4 u;
      u.x = f2bf(cur[i].x); u.y = f2bf(cur[i].y); u.z = f2bf(cur[i].z); u.w = f2bf(cur[i].w);
      *(ushortx4*)(&As[r * 72 + lm * 4]) = u;
    }
    // stage B tile (64 KB) async global->LDS: 8 gl_lds per thread
    #pragma unroll
    for (int c = 0; c < 8; ++c) {
      int kg = c & 1, ntl = (c >> 1) * 8 + w;
      const unsigned short* src = Wi_p + ((size_t)((kt * 2 + kg) * 32 + ntl) * 64 + lane) * 8;
      unsigned short* dst = &Bs[(size_t)((kg * 32 + ntl) * 64) * 8];
      gl_lds16(src, dst);
    }
    if (kt < 7) {
      // prefetch next A AFTER gl_lds (so vmcnt(4) waits only the gl_lds)
      #pragma unroll
      for (int i = 0; i < 4; ++i)
        nxt[i] = *(const floatx4*)(xbase + (size_t)i * 1048576 + (kt + 1) * 64);
      asm volatile("s_waitcnt vmcnt(4) lgkmcnt(0)" ::: "memory");
    } else {
      asm volatile("s_waitcnt vmcnt(0) lgkmcnt(0)" ::: "memory");
    }
    __builtin_amdgcn_s_barrier();
    #pragma unroll
    for (int ks = 0; ks < 2; ++ks) {
      short8 af[4];
      #pragma unroll
      for (int mt = 0; mt < 4; ++mt) {
        int m = wm * 64 + mt * 16 + lm;
        af[mt] = *(const short8*)(&As[m * 72 + ks * 32 + quad * 8]);
      }
      #pragma unroll
      for (int nt = 0; nt < 8; ++nt) {
        int g = nt >> 1, jc = nt & 1;
        int ntl = g * 8 + wn * 2 + jc;
        short8 bfv = *(const short8*)(&Bs[(size_t)((ks * 32 + ntl) * 64 + lane) * 8]);
        #pragma unroll
        for (int mt = 0; mt < 4; ++mt)
          acc[mt][nt] = __builtin_amdgcn_mfma_f32_16x16x32_bf16(af[mt], bfv, acc[mt][nt], 0, 0, 0);
      }
    }
    #pragma unroll
    for (int i = 0; i < 4; ++i) cur[i] = nxt[i];
  }
  // epilogue: per-cell 4-gate 8B stores, bias folded.
  #pragma unroll
  for (int mt = 0; mt < 4; ++mt) {
    int bbase = b0 + wm * 64 + mt * 16 + quad * 4;
    #pragma unroll
    for (int jc = 0; jc < 2; ++jc) {
      int wv = wn * 2 + jc;
      #pragma unroll
      for (int rr = 0; rr < 4; ++rr) {
        size_t cell = ((size_t)s * 64 + ((bbase + rr) >> 2)) * 512 + wv * 64 + rr * 16 + lm;
        float g0 = acc[mt][0 + jc][rr] + bs_[0][jc];
        float g1 = acc[mt][2 + jc][rr] + bs_[1][jc];
        float g2 = acc[mt][4 + jc][rr] + bs_[2][jc];
        float g3 = acc[mt][6 + jc][rr] + bs_[3][jc];
        uint2v v;
        v.x = (unsigned int)f2bf(g0) | ((unsigned int)f2bf(g1) << 16);
        v.y = (unsigned int)f2bf(g2) | ((unsigned int)f2bf(g3) << 16);
        *(uint2v*)(xg5 + cell * 2) = v;
      }
    }
  }
}

// ---------------- K3: recurrence + head ---------------------------------------
// 64 blocks x 512 threads; block bb owns batch rows bb*4..bb*4+3.
// Lane (quad,lm) of wave w owns cell (row quad, col w*16+lm) for EW/c-state.
__global__ __launch_bounds__(512, 2) void lstm_kernel(
    const unsigned int* __restrict__ xg5, const unsigned short* __restrict__ Wh_p,
    const float* __restrict__ Wd, const float* __restrict__ bd,
    float* __restrict__ out) {
  __shared__ __align__(16) unsigned short hb[2 * 16 * 140];  // 9 KB, stride 140 (8B-aligned rows)
  __shared__ __align__(16) float gbw[8 * 320];               // 10 KB wave-private transpose scratch

  const int tid = threadIdx.x;
  const int lane = tid & 63;
  const int w = tid >> 6;          // 0..7
  const int quad = lane >> 4;
  const int lm = lane & 15;
  const int bb = blockIdx.x;

  for (int i = tid; i < 2 * 16 * 140; i += 512) hb[i] = 0;

  // Wh B-fragments: gate g -> ntg = g*8 + w  (cols g*128 + w*16 + lm)
  short8 bfr[4][4];
  #pragma unroll
  for (int kk = 0; kk < 4; ++kk)
    #pragma unroll
    for (int g = 0; g < 4; ++g)
      bfr[kk][g] = *(const short8*)(Wh_p + ((size_t)(kk * 32 + g * 8 + w) * 64 + lane) * 8);

  float cst = 0.f;   // cell state for (row quad, col w*16+lm)

  // xg: cell index within block = tid; per-s stride = 64*512 cells = 32768 (x2 uints)
  const unsigned int* xp = xg5 + ((size_t)bb * 512 + tid) * 2;
  uint2v xga = *(const uint2v*)(xp);                    // s=0
  uint2v xgb = *(const uint2v*)(xp + 65536);            // s=1

  float* gw = gbw + w * 320;

  __syncthreads();   // hb zeros + initial prefetch (one-time full drain)

  auto substep = [&](const int rp, uint2v& xcur, int spre) {
    uint2v xv = xcur;
    if (spre < 512)
      xcur = *(const uint2v*)(xp + (size_t)spre * 65536);   // in flight across bar_lds

    // A-frags: 8x ds_read_b64, m=lm (batch rows; rows 4-15 read zeros)
    short8 af[4];
    #pragma unroll
    for (int kk = 0; kk < 4; ++kk) {
      const unsigned short* p = &hb[rp * 2240 + lm * 140 + kk * 32 + quad * 8];
      union { short8 v; ushortx4 h[2]; } t;
      t.h[0] = *(const ushortx4*)(p);
      t.h[1] = *(const ushortx4*)(p + 4);
      af[kk] = t.v;
    }
    floatx4 acc[4];
    #pragma unroll
    for (int g = 0; g < 4; ++g) { acc[g].x = 0.f; acc[g].y = 0.f; acc[g].z = 0.f; acc[g].w = 0.f; }
    #pragma unroll
    for (int kk = 0; kk < 4; ++kk)
      #pragma unroll
      for (int g = 0; g < 4; ++g)
        acc[g] = __builtin_amdgcn_mfma_f32_16x16x32_bf16(af[kk], bfr[kk][g], acc[g], 0, 0, 0);

    // intra-wave transpose: quad0 (rows 0-3 of C) -> [lm][r] gate-vectors
    if (lane < 16) {
      #pragma unroll
      for (int r = 0; r < 4; ++r) {
        floatx4 t4;
        t4.x = acc[0][r]; t4.y = acc[1][r]; t4.z = acc[2][r]; t4.w = acc[3][r];
        *(floatx4*)(gw + lm * 20 + r * 4) = t4;
      }
    }
    asm volatile("s_waitcnt lgkmcnt(0)" ::: "memory");   // same-wave DS order; no barrier
    floatx4 gv = *(const floatx4*)(gw + lm * 20 + quad * 4);

    // EW: 1 cell/lane
    float pre0 = gv.x + bf2f((unsigned short)(xv.x & 0xffffu));
    float pre1 = gv.y + bf2f((unsigned short)(xv.x >> 16));
    float pre2 = gv.z + bf2f((unsigned short)(xv.y & 0xffffu));
    float pre3 = gv.w + bf2f((unsigned short)(xv.y >> 16));
    float cc = sigf(pre1) * cst + sigf(pre0) * tanhf_(pre2);
    cst = cc;
    float hv = sigf(pre3) * tanhf_(cc);
    hb[(rp ^ 1) * 2240 + quad * 140 + w * 16 + lm] = f2bf(hv);
    bar_lds();   // h(s+1) visible to all; vmcnt NOT drained
  };

  for (int s = 0; s < 512; s += 2) {
    substep(0, xga, s + 2);
    substep(1, xgb, s + 3);
  }

  // head: h_last in hb buf 0 (s=511 writes buf 0)
  if (tid < 8) {
    int rw = tid >> 1, co = tid & 1;
    float a = bd[co];
    for (int j2 = 0; j2 < 128; ++j2)
      a += bf2f(hb[rw * 140 + j2]) * Wd[j2 * 2 + co];
    out[(bb * 4 + rw) * 2 + co] = a;
  }
}

extern "C" void kernel_launch(void* const* d_in, const int* in_sizes, int n_in,
                              void* d_out, int out_size, void* d_ws, size_t ws_size,
                              hipStream_t stream) {
  const float* x  = (const float*)d_in[0];
  const float* Wi = (const float*)d_in[1];
  const float* Wh = (const float*)d_in[2];
  const float* b  = (const float*)d_in[3];
  const float* Wd = (const float*)d_in[4];
  const float* bd = (const float*)d_in[5];
  float* out = (float*)d_out;

  unsigned short* Wi_p = (unsigned short*)d_ws;          // 512 KB
  unsigned short* Wh_p = Wi_p + 262144;                  // 128 KB
  unsigned int*   xg5  = (unsigned int*)(Wh_p + 65536);  // 128 MB

  pack_kernel<<<1280, 256, 0, stream>>>(Wi, Wh, Wi_p, Wh_p);
  xgemm_kernel<<<1024, 512, 0, stream>>>(x, Wi_p, b, xg5);
  lstm_kernel<<<64, 512, 0, stream>>>(xg5, Wh_p, Wd, bd, out);
}